// Round 1
// baseline (859.342 us; speedup 1.0000x reference)
//
#include <hip/hip_runtime.h>
#include <hip/hip_bf16.h>

#define DD 128
#define HH 16

// ---------------- LayerNorm: one wave per node ----------------
__global__ void ln_kernel(const float* __restrict__ x, const float* __restrict__ g,
                          const float* __restrict__ b, float* __restrict__ xn, int n_nodes) {
  int w = (blockIdx.x * blockDim.x + threadIdx.x) >> 6;
  int lane = threadIdx.x & 63;
  if (w >= n_nodes) return;
  const float* xr = x + (size_t)w * DD;
  float a0 = xr[lane], a1 = xr[lane + 64];
  float s = a0 + a1;
  #pragma unroll
  for (int o = 32; o > 0; o >>= 1) s += __shfl_down(s, o);
  s = __shfl(s, 0);
  float mu = s * (1.0f / DD);
  float d0 = a0 - mu, d1 = a1 - mu;
  float v = d0 * d0 + d1 * d1;
  #pragma unroll
  for (int o = 32; o > 0; o >>= 1) v += __shfl_down(v, o);
  v = __shfl(v, 0);
  float rstd = rsqrtf(v * (1.0f / DD) + 1e-5f);
  float* xo = xn + (size_t)w * DD;
  xo[lane]      = d0 * rstd * g[lane] + b[lane];
  xo[lane + 64] = d1 * rstd * g[lane + 64] + b[lane + 64];
}

// ---------------- xn @ [ia1_w | oa1_w] -> xw_a [N,32] ----------------
__global__ __launch_bounds__(256) void proj1_kernel(const float* __restrict__ xn,
    const float* __restrict__ ia1_w, const float* __restrict__ oa1_w,
    float* __restrict__ xw_a, int n_nodes) {
  __shared__ __align__(16) float wl[DD * 32];
  for (int i = threadIdx.x; i < DD * HH; i += 256) {
    int dd = i >> 4, jj = i & 15;
    wl[dd * 32 + jj]      = ia1_w[i];
    wl[dd * 32 + 16 + jj] = oa1_w[i];
  }
  __syncthreads();
  int t = blockIdx.x * blockDim.x + threadIdx.x;
  int n = t >> 5, j = t & 31;
  if (n >= n_nodes) return;
  const float* xr = xn + (size_t)n * DD;
  float acc = 0.f;
  #pragma unroll 8
  for (int d = 0; d < DD; ++d) acc = fmaf(xr[d], wl[d * 32 + j], acc);
  xw_a[(size_t)n * 32 + j] = acc;  // bias added after aggregation (GCNConv adds b at the end)
}

// ---------------- in-degree count (all edges, weight 1) ----------------
__global__ void deg_kernel(const int* __restrict__ dst, float* __restrict__ dega, int n_edges) {
  int e = blockIdx.x * blockDim.x + threadIdx.x;
  if (e < n_edges) atomicAdd(&dega[dst[e]], 1.0f);
}

__global__ void rsqrt_kernel(const float* __restrict__ cnt, float* __restrict__ dinv, int n_nodes) {
  int i = blockIdx.x * blockDim.x + threadIdx.x;
  if (i < n_nodes) dinv[i] = rsqrtf(cnt[i] + 1.0f);
}

// ---------------- action layer1 edge scatter: acc_a[dst] += xw_a[src]*norm ----------------
__global__ void edge1_kernel(const int* __restrict__ src, const int* __restrict__ dst,
    const float* __restrict__ xw_a, const float* __restrict__ dinva,
    float* __restrict__ acc_a, int n_edges) {
  int t = blockIdx.x * blockDim.x + threadIdx.x;
  int e = t >> 5;
  if (e >= n_edges) return;
  int j = t & 31;
  int s = src[e], d2 = dst[e];
  float n1 = dinva[s] * dinva[d2];
  atomicAdd(&acc_a[(size_t)d2 * 32 + j], xw_a[(size_t)s * 32 + j] * n1);
}

// ---------------- finish layer1 (relu) + project to layer2 xw2 [N,4] ----------------
__global__ void node1_kernel(const float* __restrict__ acc_a, const float* __restrict__ xw_a,
    const float* __restrict__ dinva, const float* __restrict__ ia1_b, const float* __restrict__ oa1_b,
    const float* __restrict__ ia2_w, const float* __restrict__ oa2_w,
    float* __restrict__ xw2_a, int n_nodes) {
  int t = blockIdx.x * blockDim.x + threadIdx.x;
  int n = t >> 5, j = t & 31;
  if (n >= n_nodes) return;
  float di = dinva[n], sw = di * di;
  float bias = (j < 16) ? ia1_b[j] : oa1_b[j - 16];
  float h = acc_a[(size_t)n * 32 + j] + xw_a[(size_t)n * 32 + j] * sw + bias;
  h = fmaxf(h, 0.f);
  float w0 = (j < 16) ? ia2_w[j * 2 + 0] : oa2_w[(j - 16) * 2 + 0];
  float w1 = (j < 16) ? ia2_w[j * 2 + 1] : oa2_w[(j - 16) * 2 + 1];
  float p0 = h * w0, p1 = h * w1;
  #pragma unroll
  for (int o = 1; o < 16; o <<= 1) { p0 += __shfl_xor(p0, o); p1 += __shfl_xor(p1, o); }
  if ((j & 15) == 0) {
    int k = j >> 4;  // 0=in, 1=out
    xw2_a[(size_t)n * 4 + k * 2 + 0] = p0;
    xw2_a[(size_t)n * 4 + k * 2 + 1] = p1;
  }
}

// ---------------- action layer2 edge scatter: acc2[dst] += xw2[src]*norm ----------------
__global__ void edge2_kernel(const int* __restrict__ src, const int* __restrict__ dst,
    const float* __restrict__ xw2_a, const float* __restrict__ dinva,
    float* __restrict__ acc2, int n_edges) {
  int t = blockIdx.x * blockDim.x + threadIdx.x;
  int e = t >> 2;
  if (e >= n_edges) return;
  int k = t & 3;
  int s = src[e], d2 = dst[e];
  float n1 = dinva[s] * dinva[d2];
  atomicAdd(&acc2[(size_t)d2 * 4 + k], xw2_a[(size_t)s * 4 + k] * n1);
}

// ---------------- logits + gumbel-hard flags ----------------
__global__ void gumbel_kernel(const float* __restrict__ acc2, const float* __restrict__ xw2_a,
    const float* __restrict__ dinva, const float* __restrict__ ia2_b, const float* __restrict__ oa2_b,
    const float* __restrict__ u_in, const float* __restrict__ u_out,
    float* __restrict__ fin, float* __restrict__ fout, int n_nodes) {
  int n = blockIdx.x * blockDim.x + threadIdx.x;
  if (n >= n_nodes) return;
  float di = dinva[n], sw = di * di;
  float li0 = acc2[(size_t)n * 4 + 0] + xw2_a[(size_t)n * 4 + 0] * sw + ia2_b[0];
  float li1 = acc2[(size_t)n * 4 + 1] + xw2_a[(size_t)n * 4 + 1] * sw + ia2_b[1];
  float lo0 = acc2[(size_t)n * 4 + 2] + xw2_a[(size_t)n * 4 + 2] * sw + oa2_b[0];
  float lo1 = acc2[(size_t)n * 4 + 3] + xw2_a[(size_t)n * 4 + 3] * sw + oa2_b[1];
  float gi0 = -logf(-logf(u_in[(size_t)n * 2 + 0] + 1e-10f) + 1e-10f);
  float gi1 = -logf(-logf(u_in[(size_t)n * 2 + 1] + 1e-10f) + 1e-10f);
  float go0 = -logf(-logf(u_out[(size_t)n * 2 + 0] + 1e-10f) + 1e-10f);
  float go1 = -logf(-logf(u_out[(size_t)n * 2 + 1] + 1e-10f) + 1e-10f);
  // argmax of softmax((l+g)/tau) == argmax of (l+g); ties -> index 0
  fin[n]  = (li0 + gi0 >= li1 + gi1) ? 1.f : 0.f;
  fout[n] = (lo0 + go0 >= lo1 + go1) ? 1.f : 0.f;
}

// ---------------- gated in-degree for final conv ----------------
__global__ void cdeg_kernel(const int* __restrict__ src, const int* __restrict__ dst,
    const float* __restrict__ fin, const float* __restrict__ fout,
    float* __restrict__ cntc, int n_edges) {
  int e = blockIdx.x * blockDim.x + threadIdx.x;
  if (e >= n_edges) return;
  int s = src[e], d2 = dst[e];
  if (fin[d2] != 0.f && fout[s] != 0.f) atomicAdd(&cntc[d2], 1.0f);
}

// ---------------- xwc = xn @ conv_w (fp32, W staged in LDS) ----------------
#define GEMM_ROWS 64
__global__ __launch_bounds__(256) void gemm_kernel(const float* __restrict__ xn,
    const float* __restrict__ W, float* __restrict__ xwc, int n_nodes) {
  __shared__ __align__(16) float wl[DD * DD];  // 64 KB
  for (int i = threadIdx.x * 4; i < DD * DD; i += 256 * 4)
    *(float4*)&wl[i] = *(const float4*)&W[i];
  __syncthreads();
  int c4 = (threadIdx.x & 31) * 4;
  int r0 = threadIdx.x >> 5;  // 0..7
  int base = blockIdx.x * GEMM_ROWS;
  for (int r = r0; r < GEMM_ROWS; r += 8) {
    int n = base + r;
    if (n >= n_nodes) break;
    const float* xr = xn + (size_t)n * DD;
    float4 acc = {0.f, 0.f, 0.f, 0.f};
    #pragma unroll 4
    for (int d = 0; d < DD; ++d) {
      float xv = xr[d];
      float4 w = *(const float4*)&wl[d * DD + c4];
      acc.x = fmaf(xv, w.x, acc.x);
      acc.y = fmaf(xv, w.y, acc.y);
      acc.z = fmaf(xv, w.z, acc.z);
      acc.w = fmaf(xv, w.w, acc.w);
    }
    *(float4*)&xwc[(size_t)n * DD + c4] = acc;
  }
}

// ---------------- fused: edge-MLP + gated conv message, scatter into out ----------------
#define BE_EPB 32
__global__ __launch_bounds__(256) void bigedge_kernel(const int* __restrict__ src,
    const int* __restrict__ dst, const float* __restrict__ ea,
    const float* __restrict__ ep_w, const float* __restrict__ ep_b,
    const float* __restrict__ xwc, const float* __restrict__ dinvc,
    const float* __restrict__ fin, const float* __restrict__ fout,
    float* __restrict__ out_acc, int n_edges) {
  __shared__ __align__(16) float wl[HH * DD];  // 8 KB
  __shared__ float bl[DD];
  for (int i = threadIdx.x; i < HH * DD; i += 256) wl[i] = ep_w[i];
  if (threadIdx.x < DD) bl[threadIdx.x] = ep_b[threadIdx.x];
  __syncthreads();
  int j = threadIdx.x & 127;
  int sub = threadIdx.x >> 7;  // 0..1
  int ebase = blockIdx.x * BE_EPB;
  for (int i = sub; i < BE_EPB; i += 2) {
    int e = ebase + i;
    if (e >= n_edges) break;
    int s = src[e], d2 = dst[e];
    const float* ear = ea + (size_t)e * HH;
    float acc = bl[j];
    #pragma unroll
    for (int k = 0; k < HH; ++k) acc = fmaf(ear[k], wl[k * DD + j], acc);
    acc = fmaxf(acc, 0.f);
    float ew = fin[d2] * fout[s];
    if (ew != 0.f) {
      float nc = dinvc[s] * dinvc[d2] * ew;
      acc = fmaf(xwc[(size_t)s * DD + j], nc, acc);
    }
    atomicAdd(&out_acc[(size_t)d2 * DD + j], acc);
  }
}

// ---------------- finalize: out = relu(acc + xwc/deg + conv_b) ----------------
__global__ void final_kernel(float* __restrict__ out_acc, const float* __restrict__ xwc,
    const float* __restrict__ dinvc, const float* __restrict__ conv_b, int n_nodes) {
  int t = blockIdx.x * blockDim.x + threadIdx.x;
  if (t >= n_nodes * DD) return;
  int n = t >> 7, j = t & 127;
  float di = dinvc[n];
  float v = out_acc[t] + xwc[t] * di * di + conv_b[j];
  out_acc[t] = fmaxf(v, 0.f);
}

extern "C" void kernel_launch(void* const* d_in, const int* in_sizes, int n_in,
                              void* d_out, int out_size, void* d_ws, size_t ws_size,
                              hipStream_t stream) {
  const float* x      = (const float*)d_in[0];
  const int*   eidx   = (const int*)d_in[1];
  const float* ea     = (const float*)d_in[2];
  const float* u_in   = (const float*)d_in[3];
  const float* u_out  = (const float*)d_in[4];
  const float* ln_g   = (const float*)d_in[5];
  const float* ln_b   = (const float*)d_in[6];
  const float* conv_w = (const float*)d_in[7];
  const float* conv_b = (const float*)d_in[8];
  const float* ep_w   = (const float*)d_in[9];
  const float* ep_b   = (const float*)d_in[10];
  const float* ia1_w  = (const float*)d_in[11];
  const float* ia1_b  = (const float*)d_in[12];
  const float* ia2_w  = (const float*)d_in[13];
  const float* ia2_b  = (const float*)d_in[14];
  const float* oa1_w  = (const float*)d_in[15];
  const float* oa1_b  = (const float*)d_in[16];
  const float* oa2_w  = (const float*)d_in[17];
  const float* oa2_b  = (const float*)d_in[18];

  const int n = in_sizes[0] / DD;
  const int E = in_sizes[1] / 2;
  const int* src = eidx;
  const int* dst = eidx + E;

  float* ws = (float*)d_ws;
  // zeroed region (first 38n floats)
  float* acc_a = ws;                          // n*32
  float* acc2  = acc_a + (size_t)n * 32;      // n*4
  float* dega  = acc2 + (size_t)n * 4;        // n
  float* cntc  = dega + n;                    // n
  // non-zeroed
  float* xn    = cntc + n;                    // n*128
  float* xw_a  = xn + (size_t)n * DD;         // n*32
  float* xw2_a = xw_a + (size_t)n * 32;       // n*4
  float* dinva = xw2_a + (size_t)n * 4;       // n
  float* dinvc = dinva + n;                   // n
  float* fin   = dinvc + n;                   // n
  float* fout  = fin + n;                     // n
  float* xwc   = fout + n;                    // n*128

  float* out_acc = (float*)d_out;

  hipMemsetAsync(d_ws, 0, (size_t)n * 38 * sizeof(float), stream);
  hipMemsetAsync(d_out, 0, (size_t)out_size * sizeof(float), stream);

  const int B = 256;
  // LayerNorm (wave per node)
  ln_kernel<<<(n * 64 + B - 1) / B, B, 0, stream>>>(x, ln_g, ln_b, xn, n);
  // action layer1 projection
  proj1_kernel<<<(n * 32 + B - 1) / B, B, 0, stream>>>(xn, ia1_w, oa1_w, xw_a, n);
  // degrees (all-ones weights)
  deg_kernel<<<(E + B - 1) / B, B, 0, stream>>>(dst, dega, E);
  rsqrt_kernel<<<(n + B - 1) / B, B, 0, stream>>>(dega, dinva, n);
  // action layer1 aggregate
  edge1_kernel<<<((size_t)E * 32 + B - 1) / B, B, 0, stream>>>(src, dst, xw_a, dinva, acc_a, E);
  node1_kernel<<<(n * 32 + B - 1) / B, B, 0, stream>>>(acc_a, xw_a, dinva, ia1_b, oa1_b,
                                                       ia2_w, oa2_w, xw2_a, n);
  // action layer2 aggregate
  edge2_kernel<<<((size_t)E * 4 + B - 1) / B, B, 0, stream>>>(src, dst, xw2_a, dinva, acc2, E);
  gumbel_kernel<<<(n + B - 1) / B, B, 0, stream>>>(acc2, xw2_a, dinva, ia2_b, oa2_b,
                                                   u_in, u_out, fin, fout, n);
  // gated degree for final conv
  cdeg_kernel<<<(E + B - 1) / B, B, 0, stream>>>(src, dst, fin, fout, cntc, E);
  rsqrt_kernel<<<(n + B - 1) / B, B, 0, stream>>>(cntc, dinvc, n);
  // conv GEMM
  gemm_kernel<<<(n + GEMM_ROWS - 1) / GEMM_ROWS, B, 0, stream>>>(xn, conv_w, xwc, n);
  // fused edge-MLP + gated message scatter
  bigedge_kernel<<<(E + BE_EPB - 1) / BE_EPB, B, 0, stream>>>(src, dst, ea, ep_w, ep_b,
                                                              xwc, dinvc, fin, fout, out_acc, E);
  // finalize
  final_kernel<<<((size_t)n * DD + B - 1) / B, B, 0, stream>>>(out_acc, xwc, dinvc, conv_b, n);
}

// Round 2
// 790.837 us; speedup vs baseline: 1.0866x; 1.0866x over previous
//
#include <hip/hip_runtime.h>
#include <hip/hip_bf16.h>

#define DD 128
#define HH 16
#define SCAN_B 1024

// ---------------- LayerNorm: one wave per node ----------------
__global__ void ln_kernel(const float* __restrict__ x, const float* __restrict__ g,
                          const float* __restrict__ b, float* __restrict__ xn, int n_nodes) {
  int w = (blockIdx.x * blockDim.x + threadIdx.x) >> 6;
  int lane = threadIdx.x & 63;
  if (w >= n_nodes) return;
  const float* xr = x + (size_t)w * DD;
  float a0 = xr[lane], a1 = xr[lane + 64];
  float s = a0 + a1;
  #pragma unroll
  for (int o = 32; o > 0; o >>= 1) s += __shfl_down(s, o);
  s = __shfl(s, 0);
  float mu = s * (1.0f / DD);
  float d0 = a0 - mu, d1 = a1 - mu;
  float v = d0 * d0 + d1 * d1;
  #pragma unroll
  for (int o = 32; o > 0; o >>= 1) v += __shfl_down(v, o);
  v = __shfl(v, 0);
  float rstd = rsqrtf(v * (1.0f / DD) + 1e-5f);
  float* xo = xn + (size_t)w * DD;
  xo[lane]      = d0 * rstd * g[lane] + b[lane];
  xo[lane + 64] = d1 * rstd * g[lane + 64] + b[lane + 64];
}

// ---------------- xn @ [ia1_w | oa1_w] -> xw_a [N,32] ----------------
__global__ __launch_bounds__(256) void proj1_kernel(const float* __restrict__ xn,
    const float* __restrict__ ia1_w, const float* __restrict__ oa1_w,
    float* __restrict__ xw_a, int n_nodes) {
  __shared__ __align__(16) float wl[DD * 32];
  for (int i = threadIdx.x; i < DD * HH; i += 256) {
    int dd = i >> 4, jj = i & 15;
    wl[dd * 32 + jj]      = ia1_w[i];
    wl[dd * 32 + 16 + jj] = oa1_w[i];
  }
  __syncthreads();
  int t = blockIdx.x * blockDim.x + threadIdx.x;
  int n = t >> 5, j = t & 31;
  if (n >= n_nodes) return;
  const float* xr = xn + (size_t)n * DD;
  float acc = 0.f;
  #pragma unroll 8
  for (int d = 0; d < DD; ++d) acc = fmaf(xr[d], wl[d * 32 + j], acc);
  xw_a[(size_t)n * 32 + j] = acc;
}

// ---------------- degree histogram (int) ----------------
__global__ void degcnt_kernel(const int* __restrict__ dst, int* __restrict__ deg, int n_edges) {
  int e = blockIdx.x * blockDim.x + threadIdx.x;
  if (e < n_edges) atomicAdd(&deg[dst[e]], 1);
}

// ---------------- 3-kernel exclusive scan over deg -> rs ----------------
__global__ __launch_bounds__(SCAN_B) void scan1_kernel(const int* __restrict__ deg,
    int* __restrict__ rs, int* __restrict__ partials, int n_nodes) {
  __shared__ int sm[SCAN_B];
  int i = blockIdx.x * SCAN_B + threadIdx.x;
  int v = (i < n_nodes) ? deg[i] : 0;
  sm[threadIdx.x] = v;
  __syncthreads();
  for (int o = 1; o < SCAN_B; o <<= 1) {
    int t = (threadIdx.x >= o) ? sm[threadIdx.x - o] : 0;
    __syncthreads();
    sm[threadIdx.x] += t;
    __syncthreads();
  }
  if (i < n_nodes) rs[i] = sm[threadIdx.x] - v;  // exclusive
  if (threadIdx.x == SCAN_B - 1) partials[blockIdx.x] = sm[threadIdx.x];
}

__global__ __launch_bounds__(SCAN_B) void scan2_kernel(int* __restrict__ partials, int nb) {
  __shared__ int sm[SCAN_B];
  int v = (threadIdx.x < nb) ? partials[threadIdx.x] : 0;
  sm[threadIdx.x] = v;
  __syncthreads();
  for (int o = 1; o < SCAN_B; o <<= 1) {
    int t = (threadIdx.x >= o) ? sm[threadIdx.x - o] : 0;
    __syncthreads();
    sm[threadIdx.x] += t;
    __syncthreads();
  }
  if (threadIdx.x < nb) partials[threadIdx.x] = sm[threadIdx.x] - v;  // exclusive
}

__global__ __launch_bounds__(SCAN_B) void scan3_kernel(int* __restrict__ rs,
    const int* __restrict__ partials, int n_nodes) {
  int i = blockIdx.x * SCAN_B + threadIdx.x;
  if (i < n_nodes) rs[i] += partials[blockIdx.x];
}

// ---------------- CSR fill: rs is mutated to end-offsets ----------------
__global__ void fill_kernel(const int* __restrict__ src, const int* __restrict__ dst,
    int* __restrict__ rs, int* __restrict__ csr_eid, int* __restrict__ csr_src, int n_edges) {
  int e = blockIdx.x * blockDim.x + threadIdx.x;
  if (e >= n_edges) return;
  int d = dst[e];
  int pos = atomicAdd(&rs[d], 1);
  csr_eid[pos] = e;
  csr_src[pos] = src[e];
}

__global__ void dinva_kernel(const int* __restrict__ deg, float* __restrict__ dinv, int n_nodes) {
  int i = blockIdx.x * blockDim.x + threadIdx.x;
  if (i < n_nodes) dinv[i] = rsqrtf((float)deg[i] + 1.0f);
}

// ---------------- action layer1 gather + relu + project to xw2 [N,4] ----------------
__global__ __launch_bounds__(256) void agg1_kernel(const int* __restrict__ rs,
    const int* __restrict__ deg, const int* __restrict__ csr_src,
    const float* __restrict__ xw_a, const float* __restrict__ dinva,
    const float* __restrict__ ia1_b, const float* __restrict__ oa1_b,
    const float* __restrict__ ia2_w, const float* __restrict__ oa2_w,
    float* __restrict__ xw2_a, int n_nodes) {
  int t = blockIdx.x * blockDim.x + threadIdx.x;
  int node = t >> 5, j = t & 31;
  if (node >= n_nodes) return;
  int dg = deg[node];
  int st = rs[node] - dg;  // rs holds end offsets after fill
  float acc = 0.f;
  for (int i = 0; i < dg; ++i) {
    int s = csr_src[st + i];
    acc = fmaf(xw_a[(size_t)s * 32 + j], dinva[s], acc);
  }
  float di = dinva[node];
  float bias = (j < 16) ? ia1_b[j] : oa1_b[j - 16];
  float h = fmaxf(acc * di + xw_a[(size_t)node * 32 + j] * di * di + bias, 0.f);
  float w0 = (j < 16) ? ia2_w[j * 2 + 0] : oa2_w[(j - 16) * 2 + 0];
  float w1 = (j < 16) ? ia2_w[j * 2 + 1] : oa2_w[(j - 16) * 2 + 1];
  float p0 = h * w0, p1 = h * w1;
  #pragma unroll
  for (int o = 1; o < 16; o <<= 1) { p0 += __shfl_xor(p0, o); p1 += __shfl_xor(p1, o); }
  if ((j & 15) == 0) {
    int k = j >> 4;  // 0=in, 1=out
    xw2_a[(size_t)node * 4 + k * 2 + 0] = p0;
    xw2_a[(size_t)node * 4 + k * 2 + 1] = p1;
  }
}

// ---------------- action layer2 gather + gumbel flags (1 thread/node) ----------------
__global__ void agg2_kernel(const int* __restrict__ rs, const int* __restrict__ deg,
    const int* __restrict__ csr_src, const float* __restrict__ xw2_a,
    const float* __restrict__ dinva, const float* __restrict__ ia2_b,
    const float* __restrict__ oa2_b, const float* __restrict__ u_in,
    const float* __restrict__ u_out, float* __restrict__ fin, float* __restrict__ fout,
    int n_nodes) {
  int node = blockIdx.x * blockDim.x + threadIdx.x;
  if (node >= n_nodes) return;
  int dg = deg[node];
  int st = rs[node] - dg;
  float a0 = 0.f, a1 = 0.f, a2 = 0.f, a3 = 0.f;
  for (int i = 0; i < dg; ++i) {
    int s = csr_src[st + i];
    float ds = dinva[s];
    float4 v = *(const float4*)&xw2_a[(size_t)s * 4];
    a0 = fmaf(v.x, ds, a0); a1 = fmaf(v.y, ds, a1);
    a2 = fmaf(v.z, ds, a2); a3 = fmaf(v.w, ds, a3);
  }
  float di = dinva[node], sw = di * di;
  float4 self = *(const float4*)&xw2_a[(size_t)node * 4];
  float li0 = a0 * di + self.x * sw + ia2_b[0];
  float li1 = a1 * di + self.y * sw + ia2_b[1];
  float lo0 = a2 * di + self.z * sw + oa2_b[0];
  float lo1 = a3 * di + self.w * sw + oa2_b[1];
  float gi0 = -logf(-logf(u_in[(size_t)node * 2 + 0] + 1e-10f) + 1e-10f);
  float gi1 = -logf(-logf(u_in[(size_t)node * 2 + 1] + 1e-10f) + 1e-10f);
  float go0 = -logf(-logf(u_out[(size_t)node * 2 + 0] + 1e-10f) + 1e-10f);
  float go1 = -logf(-logf(u_out[(size_t)node * 2 + 1] + 1e-10f) + 1e-10f);
  fin[node]  = (li0 + gi0 >= li1 + gi1) ? 1.f : 0.f;
  fout[node] = (lo0 + go0 >= lo1 + go1) ? 1.f : 0.f;
}

// ---------------- gated degree for final conv (1 thread/node) ----------------
__global__ void cdeg_kernel(const int* __restrict__ rs, const int* __restrict__ deg,
    const int* __restrict__ csr_src, const float* __restrict__ fin,
    const float* __restrict__ fout, float* __restrict__ dinvc, int n_nodes) {
  int node = blockIdx.x * blockDim.x + threadIdx.x;
  if (node >= n_nodes) return;
  int dg = deg[node];
  int st = rs[node] - dg;
  float c = 0.f;
  if (fin[node] != 0.f) {
    for (int i = 0; i < dg; ++i) c += (fout[csr_src[st + i]] != 0.f) ? 1.f : 0.f;
  }
  dinvc[node] = rsqrtf(c + 1.0f);
}

// ---------------- xwc = xn @ conv_w (fp32, W staged in LDS) ----------------
#define GEMM_ROWS 64
__global__ __launch_bounds__(256) void gemm_kernel(const float* __restrict__ xn,
    const float* __restrict__ W, float* __restrict__ xwc, int n_nodes) {
  __shared__ __align__(16) float wl[DD * DD];  // 64 KB
  for (int i = threadIdx.x * 4; i < DD * DD; i += 256 * 4)
    *(float4*)&wl[i] = *(const float4*)&W[i];
  __syncthreads();
  int c4 = (threadIdx.x & 31) * 4;
  int r0 = threadIdx.x >> 5;
  int base = blockIdx.x * GEMM_ROWS;
  for (int r = r0; r < GEMM_ROWS; r += 8) {
    int n = base + r;
    if (n >= n_nodes) break;
    const float* xr = xn + (size_t)n * DD;
    float4 acc = {0.f, 0.f, 0.f, 0.f};
    #pragma unroll 4
    for (int d = 0; d < DD; ++d) {
      float xv = xr[d];
      float4 w = *(const float4*)&wl[d * DD + c4];
      acc.x = fmaf(xv, w.x, acc.x);
      acc.y = fmaf(xv, w.y, acc.y);
      acc.z = fmaf(xv, w.z, acc.z);
      acc.w = fmaf(xv, w.w, acc.w);
    }
    *(float4*)&xwc[(size_t)n * DD + c4] = acc;
  }
}

// ---------------- fused gather: edge-MLP + gated conv + self + relu ----------------
__global__ __launch_bounds__(256) void kbig_kernel(const int* __restrict__ rs,
    const int* __restrict__ deg, const int* __restrict__ csr_src,
    const int* __restrict__ csr_eid, const float* __restrict__ ea,
    const float* __restrict__ ep_w, const float* __restrict__ ep_b,
    const float* __restrict__ xwc, const float* __restrict__ dinvc,
    const float* __restrict__ fin, const float* __restrict__ fout,
    const float* __restrict__ conv_b, float* __restrict__ out, int n_nodes) {
  __shared__ __align__(16) float wl[HH * DD];  // 8 KB
  __shared__ float bl[DD];
  for (int i = threadIdx.x; i < HH * DD; i += 256) wl[i] = ep_w[i];
  if (threadIdx.x < DD) bl[threadIdx.x] = ep_b[threadIdx.x];
  __syncthreads();
  int t = blockIdx.x * blockDim.x + threadIdx.x;
  int node = t >> 7, j = t & 127;
  if (node >= n_nodes) return;
  int dg = deg[node];
  int st = rs[node] - dg;
  float fd = fin[node];
  float dj = dinvc[node];
  float aed = 0.f, acv = 0.f;
  for (int i = 0; i < dg; ++i) {
    int e = csr_eid[st + i];
    int s = csr_src[st + i];
    const float4* ear = (const float4*)(ea + (size_t)e * HH);
    float4 e0 = ear[0], e1 = ear[1], e2 = ear[2], e3 = ear[3];
    float m = bl[j];
    m = fmaf(e0.x, wl[0 * DD + j], m);
    m = fmaf(e0.y, wl[1 * DD + j], m);
    m = fmaf(e0.z, wl[2 * DD + j], m);
    m = fmaf(e0.w, wl[3 * DD + j], m);
    m = fmaf(e1.x, wl[4 * DD + j], m);
    m = fmaf(e1.y, wl[5 * DD + j], m);
    m = fmaf(e1.z, wl[6 * DD + j], m);
    m = fmaf(e1.w, wl[7 * DD + j], m);
    m = fmaf(e2.x, wl[8 * DD + j], m);
    m = fmaf(e2.y, wl[9 * DD + j], m);
    m = fmaf(e2.z, wl[10 * DD + j], m);
    m = fmaf(e2.w, wl[11 * DD + j], m);
    m = fmaf(e3.x, wl[12 * DD + j], m);
    m = fmaf(e3.y, wl[13 * DD + j], m);
    m = fmaf(e3.z, wl[14 * DD + j], m);
    m = fmaf(e3.w, wl[15 * DD + j], m);
    aed += fmaxf(m, 0.f);
    if (fd != 0.f) {
      float fs = fout[s];
      if (fs != 0.f) acv = fmaf(xwc[(size_t)s * DD + j], dinvc[s], acv);
    }
  }
  float v = aed + acv * dj + xwc[(size_t)node * DD + j] * dj * dj + conv_b[j];
  out[(size_t)node * DD + j] = fmaxf(v, 0.f);
}

extern "C" void kernel_launch(void* const* d_in, const int* in_sizes, int n_in,
                              void* d_out, int out_size, void* d_ws, size_t ws_size,
                              hipStream_t stream) {
  const float* x      = (const float*)d_in[0];
  const int*   eidx   = (const int*)d_in[1];
  const float* ea     = (const float*)d_in[2];
  const float* u_in   = (const float*)d_in[3];
  const float* u_out  = (const float*)d_in[4];
  const float* ln_g   = (const float*)d_in[5];
  const float* ln_b   = (const float*)d_in[6];
  const float* conv_w = (const float*)d_in[7];
  const float* conv_b = (const float*)d_in[8];
  const float* ep_w   = (const float*)d_in[9];
  const float* ep_b   = (const float*)d_in[10];
  const float* ia1_w  = (const float*)d_in[11];
  const float* ia1_b  = (const float*)d_in[12];
  const float* ia2_w  = (const float*)d_in[13];
  const float* ia2_b  = (const float*)d_in[14];
  const float* oa1_w  = (const float*)d_in[15];
  const float* oa1_b  = (const float*)d_in[16];
  const float* oa2_w  = (const float*)d_in[17];
  const float* oa2_b  = (const float*)d_in[18];

  const int n = in_sizes[0] / DD;
  const int E = in_sizes[1] / 2;
  const int* src = eidx;
  const int* dst = eidx + E;

  float* ws = (float*)d_ws;
  float* xn    = ws;                         // 128n
  float* xw_a  = xn + (size_t)n * 128;       // 32n  (aliased later by fin/fout/dinvc)
  float* xw2_a = xw_a + (size_t)n * 32;      // 4n
  float* dinva = xw2_a + (size_t)n * 4;      // n
  float* xwc   = dinva + n;                  // 128n
  int* deg_i   = (int*)(xwc + (size_t)n * 128); // n (zeroed)
  int* rs      = deg_i + n;                  // n
  int* partials= rs + n;                     // 1024
  int* csr_eid = partials + 1024;            // E
  int* csr_src = csr_eid + E;                // E
  // aliases into xw_a region — written only after agg1 has consumed xw_a
  float* fin   = xw_a;
  float* fout  = xw_a + n;
  float* dinvc = xw_a + 2 * (size_t)n;

  float* out = (float*)d_out;

  hipMemsetAsync(deg_i, 0, (size_t)n * sizeof(int), stream);

  const int B = 256;
  const int nb = (n + SCAN_B - 1) / SCAN_B;

  ln_kernel<<<(n * 64 + B - 1) / B, B, 0, stream>>>(x, ln_g, ln_b, xn, n);
  proj1_kernel<<<(n * 32 + B - 1) / B, B, 0, stream>>>(xn, ia1_w, oa1_w, xw_a, n);
  degcnt_kernel<<<(E + B - 1) / B, B, 0, stream>>>(dst, deg_i, E);
  scan1_kernel<<<nb, SCAN_B, 0, stream>>>(deg_i, rs, partials, n);
  scan2_kernel<<<1, SCAN_B, 0, stream>>>(partials, nb);
  scan3_kernel<<<nb, SCAN_B, 0, stream>>>(rs, partials, n);
  dinva_kernel<<<(n + B - 1) / B, B, 0, stream>>>(deg_i, dinva, n);
  fill_kernel<<<(E + B - 1) / B, B, 0, stream>>>(src, dst, rs, csr_eid, csr_src, E);
  // after fill: rs[d] == end offset; start = rs[d] - deg[d]
  agg1_kernel<<<(n * 32 + B - 1) / B, B, 0, stream>>>(rs, deg_i, csr_src, xw_a, dinva,
                                                      ia1_b, oa1_b, ia2_w, oa2_w, xw2_a, n);
  agg2_kernel<<<(n + B - 1) / B, B, 0, stream>>>(rs, deg_i, csr_src, xw2_a, dinva,
                                                 ia2_b, oa2_b, u_in, u_out, fin, fout, n);
  cdeg_kernel<<<(n + B - 1) / B, B, 0, stream>>>(rs, deg_i, csr_src, fin, fout, dinvc, n);
  gemm_kernel<<<(n + GEMM_ROWS - 1) / GEMM_ROWS, B, 0, stream>>>(xn, conv_w, xwc, n);
  kbig_kernel<<<((size_t)n * DD + B - 1) / B, B, 0, stream>>>(rs, deg_i, csr_src, csr_eid,
      ea, ep_w, ep_b, xwc, dinvc, fin, fout, conv_b, out, n);
}

// Round 3
// 773.591 us; speedup vs baseline: 1.1108x; 1.0223x over previous
//
#include <hip/hip_runtime.h>
#include <hip/hip_bf16.h>

#define DD 128
#define HH 16
#define SCAN_B 1024
#define TPW 8  // MFMA tiles (16 edges) per wave

typedef __bf16 bf16x8 __attribute__((ext_vector_type(8)));
typedef float f32x4 __attribute__((ext_vector_type(4)));

// ---------------- LayerNorm: one wave per node ----------------
__global__ void ln_kernel(const float* __restrict__ x, const float* __restrict__ g,
                          const float* __restrict__ b, float* __restrict__ xn, int n_nodes) {
  int w = (blockIdx.x * blockDim.x + threadIdx.x) >> 6;
  int lane = threadIdx.x & 63;
  if (w >= n_nodes) return;
  const float* xr = x + (size_t)w * DD;
  float a0 = xr[lane], a1 = xr[lane + 64];
  float s = a0 + a1;
  #pragma unroll
  for (int o = 32; o > 0; o >>= 1) s += __shfl_down(s, o);
  s = __shfl(s, 0);
  float mu = s * (1.0f / DD);
  float d0 = a0 - mu, d1 = a1 - mu;
  float v = d0 * d0 + d1 * d1;
  #pragma unroll
  for (int o = 32; o > 0; o >>= 1) v += __shfl_down(v, o);
  v = __shfl(v, 0);
  float rstd = rsqrtf(v * (1.0f / DD) + 1e-5f);
  float* xo = xn + (size_t)w * DD;
  xo[lane]      = d0 * rstd * g[lane] + b[lane];
  xo[lane + 64] = d1 * rstd * g[lane + 64] + b[lane + 64];
}

// ---------------- xn @ [ia1_w | oa1_w] -> xw_a [N,32] ----------------
__global__ __launch_bounds__(256) void proj1_kernel(const float* __restrict__ xn,
    const float* __restrict__ ia1_w, const float* __restrict__ oa1_w,
    float* __restrict__ xw_a, int n_nodes) {
  __shared__ __align__(16) float wl[DD * 32];
  for (int i = threadIdx.x; i < DD * HH; i += 256) {
    int dd = i >> 4, jj = i & 15;
    wl[dd * 32 + jj]      = ia1_w[i];
    wl[dd * 32 + 16 + jj] = oa1_w[i];
  }
  __syncthreads();
  int t = blockIdx.x * blockDim.x + threadIdx.x;
  int n = t >> 5, j = t & 31;
  if (n >= n_nodes) return;
  const float* xr = xn + (size_t)n * DD;
  float acc = 0.f;
  #pragma unroll 8
  for (int d = 0; d < DD; ++d) acc = fmaf(xr[d], wl[d * 32 + j], acc);
  xw_a[(size_t)n * 32 + j] = acc;
}

// ---------------- degree histogram (int) ----------------
__global__ void degcnt_kernel(const int* __restrict__ dst, int* __restrict__ deg, int n_edges) {
  int e = blockIdx.x * blockDim.x + threadIdx.x;
  if (e < n_edges) atomicAdd(&deg[dst[e]], 1);
}

// ---------------- 3-kernel exclusive scan over deg -> rs ----------------
__global__ __launch_bounds__(SCAN_B) void scan1_kernel(const int* __restrict__ deg,
    int* __restrict__ rs, int* __restrict__ partials, int n_nodes) {
  __shared__ int sm[SCAN_B];
  int i = blockIdx.x * SCAN_B + threadIdx.x;
  int v = (i < n_nodes) ? deg[i] : 0;
  sm[threadIdx.x] = v;
  __syncthreads();
  for (int o = 1; o < SCAN_B; o <<= 1) {
    int t = (threadIdx.x >= o) ? sm[threadIdx.x - o] : 0;
    __syncthreads();
    sm[threadIdx.x] += t;
    __syncthreads();
  }
  if (i < n_nodes) rs[i] = sm[threadIdx.x] - v;  // exclusive
  if (threadIdx.x == SCAN_B - 1) partials[blockIdx.x] = sm[threadIdx.x];
}

__global__ __launch_bounds__(SCAN_B) void scan2_kernel(int* __restrict__ partials, int nb) {
  __shared__ int sm[SCAN_B];
  int v = (threadIdx.x < nb) ? partials[threadIdx.x] : 0;
  sm[threadIdx.x] = v;
  __syncthreads();
  for (int o = 1; o < SCAN_B; o <<= 1) {
    int t = (threadIdx.x >= o) ? sm[threadIdx.x - o] : 0;
    __syncthreads();
    sm[threadIdx.x] += t;
    __syncthreads();
  }
  if (threadIdx.x < nb) partials[threadIdx.x] = sm[threadIdx.x] - v;  // exclusive
}

__global__ __launch_bounds__(SCAN_B) void scan3_kernel(int* __restrict__ rs,
    const int* __restrict__ partials, int n_nodes) {
  int i = blockIdx.x * SCAN_B + threadIdx.x;
  if (i < n_nodes) rs[i] += partials[blockIdx.x];
}

// ---------------- CSR fill: rs is mutated to end-offsets ----------------
__global__ void fill_kernel(const int* __restrict__ src, const int* __restrict__ dst,
    int* __restrict__ rs, int* __restrict__ csr_eid, int* __restrict__ csr_src, int n_edges) {
  int e = blockIdx.x * blockDim.x + threadIdx.x;
  if (e >= n_edges) return;
  int d = dst[e];
  int pos = atomicAdd(&rs[d], 1);
  csr_eid[pos] = e;
  csr_src[pos] = src[e];
}

__global__ void dinva_kernel(const int* __restrict__ deg, float* __restrict__ dinv, int n_nodes) {
  int i = blockIdx.x * blockDim.x + threadIdx.x;
  if (i < n_nodes) dinv[i] = rsqrtf((float)deg[i] + 1.0f);
}

// ---------------- action layer1 gather + relu + project to xw2 [N,4] ----------------
__global__ __launch_bounds__(256) void agg1_kernel(const int* __restrict__ rs,
    const int* __restrict__ deg, const int* __restrict__ csr_src,
    const float* __restrict__ xw_a, const float* __restrict__ dinva,
    const float* __restrict__ ia1_b, const float* __restrict__ oa1_b,
    const float* __restrict__ ia2_w, const float* __restrict__ oa2_w,
    float* __restrict__ xw2_a, int n_nodes) {
  int t = blockIdx.x * blockDim.x + threadIdx.x;
  int node = t >> 5, j = t & 31;
  if (node >= n_nodes) return;
  int dg = deg[node];
  int st = rs[node] - dg;  // rs holds end offsets after fill
  float acc = 0.f;
  for (int i = 0; i < dg; ++i) {
    int s = csr_src[st + i];
    acc = fmaf(xw_a[(size_t)s * 32 + j], dinva[s], acc);
  }
  float di = dinva[node];
  float bias = (j < 16) ? ia1_b[j] : oa1_b[j - 16];
  float h = fmaxf(acc * di + xw_a[(size_t)node * 32 + j] * di * di + bias, 0.f);
  float w0 = (j < 16) ? ia2_w[j * 2 + 0] : oa2_w[(j - 16) * 2 + 0];
  float w1 = (j < 16) ? ia2_w[j * 2 + 1] : oa2_w[(j - 16) * 2 + 1];
  float p0 = h * w0, p1 = h * w1;
  #pragma unroll
  for (int o = 1; o < 16; o <<= 1) { p0 += __shfl_xor(p0, o); p1 += __shfl_xor(p1, o); }
  if ((j & 15) == 0) {
    int k = j >> 4;  // 0=in, 1=out
    xw2_a[(size_t)node * 4 + k * 2 + 0] = p0;
    xw2_a[(size_t)node * 4 + k * 2 + 1] = p1;
  }
}

// ---------------- action layer2 gather + gumbel flags (16 lanes/node) ----------------
__global__ void agg2_kernel(const int* __restrict__ rs, const int* __restrict__ deg,
    const int* __restrict__ csr_src, const float* __restrict__ xw2_a,
    const float* __restrict__ dinva, const float* __restrict__ ia2_b,
    const float* __restrict__ oa2_b, const float* __restrict__ u_in,
    const float* __restrict__ u_out, float* __restrict__ fin, float* __restrict__ fout,
    int n_nodes) {
  int t = blockIdx.x * blockDim.x + threadIdx.x;
  int node = t >> 4, l = t & 15;
  if (node >= n_nodes) return;
  int dg = deg[node];
  int st = rs[node] - dg;
  float a0 = 0.f, a1 = 0.f, a2 = 0.f, a3 = 0.f;
  for (int i = l; i < dg; i += 16) {
    int s = csr_src[st + i];
    float ds = dinva[s];
    float4 v = *(const float4*)&xw2_a[(size_t)s * 4];
    a0 = fmaf(v.x, ds, a0); a1 = fmaf(v.y, ds, a1);
    a2 = fmaf(v.z, ds, a2); a3 = fmaf(v.w, ds, a3);
  }
  #pragma unroll
  for (int o = 1; o < 16; o <<= 1) {
    a0 += __shfl_xor(a0, o); a1 += __shfl_xor(a1, o);
    a2 += __shfl_xor(a2, o); a3 += __shfl_xor(a3, o);
  }
  if (l == 0) {
    float di = dinva[node], sw = di * di;
    float4 self = *(const float4*)&xw2_a[(size_t)node * 4];
    float li0 = a0 * di + self.x * sw + ia2_b[0];
    float li1 = a1 * di + self.y * sw + ia2_b[1];
    float lo0 = a2 * di + self.z * sw + oa2_b[0];
    float lo1 = a3 * di + self.w * sw + oa2_b[1];
    float gi0 = -logf(-logf(u_in[(size_t)node * 2 + 0] + 1e-10f) + 1e-10f);
    float gi1 = -logf(-logf(u_in[(size_t)node * 2 + 1] + 1e-10f) + 1e-10f);
    float go0 = -logf(-logf(u_out[(size_t)node * 2 + 0] + 1e-10f) + 1e-10f);
    float go1 = -logf(-logf(u_out[(size_t)node * 2 + 1] + 1e-10f) + 1e-10f);
    fin[node]  = (li0 + gi0 >= li1 + gi1) ? 1.f : 0.f;
    fout[node] = (lo0 + go0 >= lo1 + go1) ? 1.f : 0.f;
  }
}

// ---------------- gated degree for final conv (16 lanes/node) ----------------
__global__ void cdeg_kernel(const int* __restrict__ rs, const int* __restrict__ deg,
    const int* __restrict__ csr_src, const float* __restrict__ fin,
    const float* __restrict__ fout, float* __restrict__ dinvc, int n_nodes) {
  int t = blockIdx.x * blockDim.x + threadIdx.x;
  int node = t >> 4, l = t & 15;
  if (node >= n_nodes) return;
  int dg = deg[node];
  int st = rs[node] - dg;
  float c = 0.f;
  if (fin[node] != 0.f) {
    for (int i = l; i < dg; i += 16) c += (fout[csr_src[st + i]] != 0.f) ? 1.f : 0.f;
  }
  #pragma unroll
  for (int o = 1; o < 16; o <<= 1) c += __shfl_xor(c, o);
  if (l == 0) dinvc[node] = rsqrtf(c + 1.0f);
}

// ---------------- xwc = xn @ conv_w (fp32, W staged in LDS) ----------------
#define GEMM_ROWS 64
__global__ __launch_bounds__(256) void gemm_kernel(const float* __restrict__ xn,
    const float* __restrict__ W, float* __restrict__ xwc, int n_nodes) {
  __shared__ __align__(16) float wl[DD * DD];  // 64 KB
  for (int i = threadIdx.x * 4; i < DD * DD; i += 256 * 4)
    *(float4*)&wl[i] = *(const float4*)&W[i];
  __syncthreads();
  int c4 = (threadIdx.x & 31) * 4;
  int r0 = threadIdx.x >> 5;
  int base = blockIdx.x * GEMM_ROWS;
  for (int r = r0; r < GEMM_ROWS; r += 8) {
    int n = base + r;
    if (n >= n_nodes) break;
    const float* xr = xn + (size_t)n * DD;
    float4 acc = {0.f, 0.f, 0.f, 0.f};
    #pragma unroll 4
    for (int d = 0; d < DD; ++d) {
      float xv = xr[d];
      float4 w = *(const float4*)&wl[d * DD + c4];
      acc.x = fmaf(xv, w.x, acc.x);
      acc.y = fmaf(xv, w.y, acc.y);
      acc.z = fmaf(xv, w.z, acc.z);
      acc.w = fmaf(xv, w.w, acc.w);
    }
    *(float4*)&xwc[(size_t)n * DD + c4] = acc;
  }
}

// ---------------- edge MLP via MFMA: ef[pos][j] = relu(ea[eid]@W + b), CSR order, bf16 ----------------
__global__ __launch_bounds__(256) void mlp_kernel(const int* __restrict__ csr_eid,
    const float* __restrict__ ea, const float* __restrict__ ep_w,
    const float* __restrict__ ep_b, __bf16* __restrict__ ef, int n_edges) {
  int l = threadIdx.x & 63;
  int wave_g = (blockIdx.x * 256 + threadIdx.x) >> 6;
  int tile0 = wave_g * TPW;
  int col = l & 15;       // A row (edge) / B col (j) / D col (j)
  int kg = l >> 4;        // 0..3
  int k0 = kg * 8;
  bool a_active = (k0 < HH);
  // B fragments (W) + bias, held in registers for the whole strip
  bf16x8 bfr[8];
  float bias[8];
  #pragma unroll
  for (int nt = 0; nt < 8; ++nt) {
    int j = nt * 16 + col;
    bf16x8 bb;
    #pragma unroll
    for (int i = 0; i < 8; ++i) {
      int k = k0 + i;
      bb[i] = (__bf16)((k < HH) ? ep_w[k * DD + j] : 0.f);
    }
    bfr[nt] = bb;
    bias[nt] = ep_b[j];
  }
  for (int t = 0; t < TPW; ++t) {
    int pos0 = (tile0 + t) * 16;
    if (pos0 >= n_edges) return;
    int apos = pos0 + col;
    int eid = csr_eid[(apos < n_edges) ? apos : (n_edges - 1)];
    bf16x8 afr = {};
    if (a_active) {
      const float4* er = (const float4*)(ea + (size_t)eid * HH + k0);
      float4 f0 = er[0], f1 = er[1];
      afr[0] = (__bf16)f0.x; afr[1] = (__bf16)f0.y;
      afr[2] = (__bf16)f0.z; afr[3] = (__bf16)f0.w;
      afr[4] = (__bf16)f1.x; afr[5] = (__bf16)f1.y;
      afr[6] = (__bf16)f1.z; afr[7] = (__bf16)f1.w;
    }
    #pragma unroll
    for (int nt = 0; nt < 8; ++nt) {
      f32x4 d = {0.f, 0.f, 0.f, 0.f};
      d = __builtin_amdgcn_mfma_f32_16x16x32_bf16(afr, bfr[nt], d, 0, 0, 0);
      int j = nt * 16 + col;
      #pragma unroll
      for (int r = 0; r < 4; ++r) {
        int pos = pos0 + kg * 4 + r;     // D row = (lane>>4)*4 + r
        if (pos < n_edges)
          ef[(size_t)pos * DD + j] = (__bf16)fmaxf(d[r] + bias[nt], 0.f);
      }
    }
  }
}

// ---------------- final gather: wave per node, lane = j-pair ----------------
__global__ __launch_bounds__(256) void kbig_kernel(const int* __restrict__ rs,
    const int* __restrict__ deg, const int* __restrict__ csr_src,
    const __bf16* __restrict__ ef, const float* __restrict__ xwc,
    const float* __restrict__ dinvc, const float* __restrict__ fin,
    const float* __restrict__ fout, const float* __restrict__ conv_b,
    float* __restrict__ out, int n_nodes) {
  int node = (blockIdx.x * blockDim.x + threadIdx.x) >> 6;
  int l = threadIdx.x & 63;
  if (node >= n_nodes) return;
  int dg = deg[node];
  int st = rs[node] - dg;
  float fd = fin[node];
  float dj = dinvc[node];
  float a0 = 0.f, a1 = 0.f, c0 = 0.f, c1 = 0.f;
  for (int i = 0; i < dg; ++i) {
    int pos = st + i;
    unsigned u = *(const unsigned*)(ef + (size_t)pos * DD + 2 * l);
    a0 += __uint_as_float(u << 16);
    a1 += __uint_as_float(u & 0xffff0000u);
    if (fd != 0.f) {
      int s = csr_src[pos];
      if (fout[s] != 0.f) {
        float2 w = *(const float2*)(xwc + (size_t)s * DD + 2 * l);
        float ds = dinvc[s];
        c0 = fmaf(w.x, ds, c0);
        c1 = fmaf(w.y, ds, c1);
      }
    }
  }
  float2 selfw = *(const float2*)(xwc + (size_t)node * DD + 2 * l);
  float2 cb = *(const float2*)(conv_b + 2 * l);
  float o0 = a0 + c0 * dj + selfw.x * dj * dj + cb.x;
  float o1 = a1 + c1 * dj + selfw.y * dj * dj + cb.y;
  float2 res = {fmaxf(o0, 0.f), fmaxf(o1, 0.f)};
  *(float2*)(out + (size_t)node * DD + 2 * l) = res;
}

// ---------------- fallback (small ws): round-2 fused kbig ----------------
__global__ __launch_bounds__(256) void kbig_fused_kernel(const int* __restrict__ rs,
    const int* __restrict__ deg, const int* __restrict__ csr_src,
    const int* __restrict__ csr_eid, const float* __restrict__ ea,
    const float* __restrict__ ep_w, const float* __restrict__ ep_b,
    const float* __restrict__ xwc, const float* __restrict__ dinvc,
    const float* __restrict__ fin, const float* __restrict__ fout,
    const float* __restrict__ conv_b, float* __restrict__ out, int n_nodes) {
  __shared__ __align__(16) float wl[HH * DD];
  __shared__ float bl[DD];
  for (int i = threadIdx.x; i < HH * DD; i += 256) wl[i] = ep_w[i];
  if (threadIdx.x < DD) bl[threadIdx.x] = ep_b[threadIdx.x];
  __syncthreads();
  int t = blockIdx.x * blockDim.x + threadIdx.x;
  int node = t >> 7, j = t & 127;
  if (node >= n_nodes) return;
  int dg = deg[node];
  int st = rs[node] - dg;
  float fd = fin[node];
  float dj = dinvc[node];
  float aed = 0.f, acv = 0.f;
  for (int i = 0; i < dg; ++i) {
    int e = csr_eid[st + i];
    int s = csr_src[st + i];
    const float4* ear = (const float4*)(ea + (size_t)e * HH);
    float4 e0 = ear[0], e1 = ear[1], e2 = ear[2], e3 = ear[3];
    float m = bl[j];
    m = fmaf(e0.x, wl[0 * DD + j], m); m = fmaf(e0.y, wl[1 * DD + j], m);
    m = fmaf(e0.z, wl[2 * DD + j], m); m = fmaf(e0.w, wl[3 * DD + j], m);
    m = fmaf(e1.x, wl[4 * DD + j], m); m = fmaf(e1.y, wl[5 * DD + j], m);
    m = fmaf(e1.z, wl[6 * DD + j], m); m = fmaf(e1.w, wl[7 * DD + j], m);
    m = fmaf(e2.x, wl[8 * DD + j], m); m = fmaf(e2.y, wl[9 * DD + j], m);
    m = fmaf(e2.z, wl[10 * DD + j], m); m = fmaf(e2.w, wl[11 * DD + j], m);
    m = fmaf(e3.x, wl[12 * DD + j], m); m = fmaf(e3.y, wl[13 * DD + j], m);
    m = fmaf(e3.z, wl[14 * DD + j], m); m = fmaf(e3.w, wl[15 * DD + j], m);
    aed += fmaxf(m, 0.f);
    if (fd != 0.f) {
      if (fout[s] != 0.f) acv = fmaf(xwc[(size_t)s * DD + j], dinvc[s], acv);
    }
  }
  float v = aed + acv * dj + xwc[(size_t)node * DD + j] * dj * dj + conv_b[j];
  out[(size_t)node * DD + j] = fmaxf(v, 0.f);
}

extern "C" void kernel_launch(void* const* d_in, const int* in_sizes, int n_in,
                              void* d_out, int out_size, void* d_ws, size_t ws_size,
                              hipStream_t stream) {
  const float* x      = (const float*)d_in[0];
  const int*   eidx   = (const int*)d_in[1];
  const float* ea     = (const float*)d_in[2];
  const float* u_in   = (const float*)d_in[3];
  const float* u_out  = (const float*)d_in[4];
  const float* ln_g   = (const float*)d_in[5];
  const float* ln_b   = (const float*)d_in[6];
  const float* conv_w = (const float*)d_in[7];
  const float* conv_b = (const float*)d_in[8];
  const float* ep_w   = (const float*)d_in[9];
  const float* ep_b   = (const float*)d_in[10];
  const float* ia1_w  = (const float*)d_in[11];
  const float* ia1_b  = (const float*)d_in[12];
  const float* ia2_w  = (const float*)d_in[13];
  const float* ia2_b  = (const float*)d_in[14];
  const float* oa1_w  = (const float*)d_in[15];
  const float* oa1_b  = (const float*)d_in[16];
  const float* oa2_w  = (const float*)d_in[17];
  const float* oa2_b  = (const float*)d_in[18];

  const int n = in_sizes[0] / DD;
  const int E = in_sizes[1] / 2;
  const int* src = eidx;
  const int* dst = eidx + E;

  float* ws = (float*)d_ws;
  float* xn    = ws;                            // 128n
  float* xw_a  = xn + (size_t)n * 128;          // 32n (aliased later by fin/fout/dinvc)
  float* xw2_a = xw_a + (size_t)n * 32;         // 4n
  float* dinva = xw2_a + (size_t)n * 4;         // n
  float* xwc   = dinva + n;                     // 128n
  int* deg_i   = (int*)(xwc + (size_t)n * 128); // n (zeroed)
  int* rs      = deg_i + n;                     // n
  int* partials= rs + n;                        // 1024
  int* csr_eid = partials + 1024;               // E
  int* csr_src = csr_eid + E;                   // E
  __bf16* ef   = (__bf16*)(csr_src + E);        // E*128 bf16
  float* fin   = xw_a;
  float* fout  = xw_a + n;
  float* dinvc = xw_a + 2 * (size_t)n;

  float* out = (float*)d_out;

  size_t need = ((size_t)n * 295 + 2 * (size_t)E + 1024) * 4 + (size_t)E * DD * 2;
  bool big_ws = ws_size >= need;

  hipMemsetAsync(deg_i, 0, (size_t)n * sizeof(int), stream);

  const int B = 256;
  const int nb = (n + SCAN_B - 1) / SCAN_B;

  ln_kernel<<<(n * 64 + B - 1) / B, B, 0, stream>>>(x, ln_g, ln_b, xn, n);
  proj1_kernel<<<(n * 32 + B - 1) / B, B, 0, stream>>>(xn, ia1_w, oa1_w, xw_a, n);
  degcnt_kernel<<<(E + B - 1) / B, B, 0, stream>>>(dst, deg_i, E);
  scan1_kernel<<<nb, SCAN_B, 0, stream>>>(deg_i, rs, partials, n);
  scan2_kernel<<<1, SCAN_B, 0, stream>>>(partials, nb);
  scan3_kernel<<<nb, SCAN_B, 0, stream>>>(rs, partials, n);
  dinva_kernel<<<(n + B - 1) / B, B, 0, stream>>>(deg_i, dinva, n);
  fill_kernel<<<(E + B - 1) / B, B, 0, stream>>>(src, dst, rs, csr_eid, csr_src, E);
  // after fill: rs[d] == end offset; start = rs[d] - deg[d]
  agg1_kernel<<<(n * 32 + B - 1) / B, B, 0, stream>>>(rs, deg_i, csr_src, xw_a, dinva,
                                                      ia1_b, oa1_b, ia2_w, oa2_w, xw2_a, n);
  agg2_kernel<<<(n * 16 + B - 1) / B, B, 0, stream>>>(rs, deg_i, csr_src, xw2_a, dinva,
                                                      ia2_b, oa2_b, u_in, u_out, fin, fout, n);
  cdeg_kernel<<<(n * 16 + B - 1) / B, B, 0, stream>>>(rs, deg_i, csr_src, fin, fout, dinvc, n);
  gemm_kernel<<<(n + GEMM_ROWS - 1) / GEMM_ROWS, B, 0, stream>>>(xn, conv_w, xwc, n);

  if (big_ws) {
    int tiles = (E + 15) / 16;
    int nwaves = (tiles + TPW - 1) / TPW;
    int nblocks = (nwaves + 3) / 4;
    mlp_kernel<<<nblocks, B, 0, stream>>>(csr_eid, ea, ep_w, ep_b, ef, E);
    kbig_kernel<<<((size_t)n * 64 + B - 1) / B, B, 0, stream>>>(rs, deg_i, csr_src, ef,
        xwc, dinvc, fin, fout, conv_b, out, n);
  } else {
    kbig_fused_kernel<<<((size_t)n * DD + B - 1) / B, B, 0, stream>>>(rs, deg_i, csr_src,
        csr_eid, ea, ep_w, ep_b, xwc, dinvc, fin, fout, conv_b, out, n);
  }
}